// Round 3
// baseline (964.260 us; speedup 1.0000x reference)
//
#include <hip/hip_runtime.h>

#define EPSF 1e-8f

typedef __attribute__((ext_vector_type(8))) short bf16x8;
typedef __attribute__((ext_vector_type(16))) float f32x16;

constexpr int Nv     = 10000;  // N
constexpr int Ne     = 5000;   // E
constexpr int Dd     = 128;    // d
constexpr int NPAD   = 10016;  // 626*16, K padded
constexpr int NT16   = 626;    // K-steps of 16
constexpr int ETILES = 157;    // ceil(5000/32)
constexpr int EW     = ETILES * 32;   // 5024
constexpr int KSPLIT = 16;     // 157*16 = 2512 waves = 628 blocks of 4 waves

__device__ __forceinline__ unsigned short f2bf_rne(float f) {
    unsigned int u = __builtin_bit_cast(unsigned int, f);
    u += 0x7fffu + ((u >> 16) & 1u);
    return (unsigned short)(u >> 16);
}

// dvis[n] = (Dv[n,n]+eps)^-1/2 (0 in pad); de_inv[e] = 1/(De[e,e]+eps) (0 in pad)
__global__ void prep_diag_kernel(const float* __restrict__ Dv, const float* __restrict__ De,
                                 float* __restrict__ dvis, float* __restrict__ de_inv) {
    int i = blockIdx.x * 256 + threadIdx.x;
    if (i < NPAD) dvis[i] = (i < Nv) ? rsqrtf(Dv[(size_t)i * (Nv + 1)] + EPSF) : 0.0f;
    if (i < EW)   de_inv[i] = (i < Ne) ? 1.0f / (De[(size_t)i * (Ne + 1)] + EPSF) : 0.0f;
}

// Fst[c][n] = bf16(F[n,c]*dvis[n]) (A-operand layout, n-contiguous) + fused sum(F*F)
__global__ void prep_fst_kernel(const float* __restrict__ F, const float* __restrict__ dvis,
                                short* __restrict__ Fst, float* __restrict__ out0) {
    int n = blockIdx.x * 256 + threadIdx.x;
    int c = blockIdx.y;
    float v = 0.0f;
    if (n < NPAD) {
        unsigned short b = 0;
        if (n < Nv) { v = F[(size_t)n * Dd + c]; b = f2bf_rne(v * dvis[n]); }
        Fst[(size_t)c * NPAD + n] = (short)b;
    }
    float sum = v * v;
    #pragma unroll
    for (int off = 32; off; off >>= 1) sum += __shfl_down(sum, off);
    if ((threadIdx.x & 63) == 0) atomicAdd(out0, sum);
}

// Split-K GEMM, no LDS, no barriers.
// B = H (fp32->bf16 in regs): B[k=n][col=e], lanes span 32 consecutive e -> coalesced.
// A = Fst (bf16, L1/L2-hot): A[m=c][k=n], 16B contiguous per lane.
// Each wave: one 32-e tile x full 128 c (4 MFMAs/step, H reused 4x per load).
__global__ __launch_bounds__(256, 4)
void gemm_kernel(const float* __restrict__ H, const short* __restrict__ Fst,
                 float* __restrict__ Mp) {
    const int t    = threadIdx.x;
    const int w    = t >> 6;
    const int l    = t & 63;
    const int em   = l & 31;              // e / m lane index
    const int half = l >> 5;              // k-half
    const int gw   = blockIdx.x * 4 + w;  // 0..2511
    const int et   = gw % ETILES;
    const int spl  = gw / ETILES;         // 0..15
    const int e    = et * 32 + em;
    const bool ev  = (e < Ne);
    const int sb   = (spl * NT16) / KSPLIT;
    const int se   = ((spl + 1) * NT16) / KSPLIT;

    f32x16 acc[4];
    #pragma unroll
    for (int ct = 0; ct < 4; ++ct) acc[ct] = (f32x16)(0.0f);

    float bc[8], bn[8];
    auto loadB = [&](int s, float* b) {
        const int kb = s * 16 + half * 8;
        #pragma unroll
        for (int j = 0; j < 8; ++j) {
            const int n = kb + j;
            b[j] = (ev && n < Nv) ? H[(size_t)n * Ne + e] : 0.0f;
        }
    };

    loadB(sb, bc);
    for (int s = sb; s < se; ++s) {
        #pragma unroll
        for (int j = 0; j < 8; ++j) bn[j] = 0.0f;
        if (s + 1 < se) loadB(s + 1, bn);   // prefetch overlaps MFMAs

        bf16x8 Bf;
        #pragma unroll
        for (int j = 0; j < 8; ++j) Bf[j] = (short)f2bf_rne(bc[j]);

        const int kb = s * 16 + half * 8;
        bf16x8 Af[4];
        #pragma unroll
        for (int ct = 0; ct < 4; ++ct)
            Af[ct] = *(const bf16x8*)(Fst + (size_t)(ct * 32 + em) * NPAD + kb);

        #pragma unroll
        for (int ct = 0; ct < 4; ++ct)
            acc[ct] = __builtin_amdgcn_mfma_f32_32x32x16_bf16(Af[ct], Bf, acc[ct], 0, 0, 0);

        #pragma unroll
        for (int j = 0; j < 8; ++j) bc[j] = bn[j];
    }

    // D layout (32x32, HW-verified): col = lane&31, row = (reg&3) + 8*(reg>>2) + 4*(lane>>5)
    float* dst = Mp + (size_t)spl * 128 * EW;
    #pragma unroll
    for (int ct = 0; ct < 4; ++ct)
        #pragma unroll
        for (int r = 0; r < 16; ++r) {
            const int cl = (r & 3) + 8 * (r >> 2) + 4 * half;
            dst[(size_t)(ct * 32 + cl) * EW + e] = acc[ct][r];
        }
}

// S = sum_e de_inv[e] * sum_c (sum_spl Mp[spl][c][e])^2
__global__ void reduce_m_kernel(const float* __restrict__ Mp, const float* __restrict__ de_inv,
                                float* __restrict__ outS) {
    int gid = blockIdx.x * 256 + threadIdx.x;   // 628*256 = 160768 = 128 * (EW/4)
    int c   = gid / (EW / 4);
    int ei  = (gid % (EW / 4)) * 4;
    float4 m = {0.f, 0.f, 0.f, 0.f};
    #pragma unroll
    for (int sp = 0; sp < KSPLIT; ++sp) {
        float4 p = *(const float4*)(Mp + ((size_t)sp * 128 + c) * EW + ei);
        m.x += p.x; m.y += p.y; m.z += p.z; m.w += p.w;
    }
    float4 w4 = *(const float4*)(de_inv + ei);
    float sum = w4.x*m.x*m.x + w4.y*m.y*m.y + w4.z*m.z*m.z + w4.w*m.w*m.w;
    #pragma unroll
    for (int off = 32; off; off >>= 1) sum += __shfl_down(sum, off);
    if ((threadIdx.x & 63) == 0) atomicAdd(outS, sum);
}

__global__ void final_kernel(const float* __restrict__ ws0, float* __restrict__ out) {
    out[0] = (ws0[0] - ws0[1]) * (1.0f / (float)Nv);
}

extern "C" void kernel_launch(void* const* d_in, const int* in_sizes, int n_in,
                              void* d_out, int out_size, void* d_ws, size_t ws_size,
                              hipStream_t stream) {
    (void)in_sizes; (void)n_in; (void)out_size; (void)ws_size;
    const float* F  = (const float*)d_in[0];
    const float* H  = (const float*)d_in[1];
    const float* Dv = (const float*)d_in[2];
    const float* De = (const float*)d_in[3];
    float* out = (float*)d_out;

    // ws: ws0(16f) | dvis[NPAD] | de_inv[EW] | Mp[KSPLIT*128*EW] | Fst bf16[128*NPAD]
    float* ws0    = (float*)d_ws;
    float* dvis   = ws0 + 16;
    float* de_inv = dvis + NPAD;                  // byte off 40128 (16B-aligned)
    float* Mp     = de_inv + EW;                  // byte off 60224 (16B-aligned)
    short* Fst    = (short*)(Mp + (size_t)KSPLIT * 128 * EW);

    hipMemsetAsync(ws0, 0, 64, stream);           // scalar accumulators only

    prep_diag_kernel<<<(NPAD + 255) / 256, 256, 0, stream>>>(Dv, De, dvis, de_inv);
    prep_fst_kernel <<<dim3((NPAD + 255) / 256, 128), 256, 0, stream>>>(F, dvis, Fst, ws0);
    gemm_kernel     <<<(ETILES * KSPLIT) / 4, 256, 0, stream>>>(H, Fst, Mp);
    reduce_m_kernel <<<(128 * EW / 4) / 256, 256, 0, stream>>>(Mp, de_inv, ws0 + 1);
    final_kernel    <<<1, 1, 0, stream>>>(ws0, out);
}

// Round 4
// 712.252 us; speedup vs baseline: 1.3538x; 1.3538x over previous
//
#include <hip/hip_runtime.h>

#define EPSF 1e-8f

typedef __attribute__((ext_vector_type(8))) short bf16x8;
typedef __attribute__((ext_vector_type(16))) float f32x16;

constexpr int Nv     = 10000;  // N
constexpr int Ne     = 5000;   // E
constexpr int Dd     = 128;    // d
constexpr int NPAD   = 10240;  // 640*16 (pad so every split has exactly 40 steps)
constexpr int NT16   = 640;    // K-steps of 16
constexpr int ETILES = 157;    // ceil(5000/32)
constexpr int EW     = ETILES * 32;   // 5024
constexpr int KSPLIT = 16;
constexpr int SPS    = NT16 / KSPLIT; // 40 steps per split (even -> clean dbuf)

__device__ __forceinline__ unsigned short f2bf_rne(float f) {
    unsigned int u = __builtin_bit_cast(unsigned int, f);
    u += 0x7fffu + ((u >> 16) & 1u);
    return (unsigned short)(u >> 16);
}
__device__ __forceinline__ unsigned int pack2(float a, float b) {
    return (unsigned int)f2bf_rne(a) | ((unsigned int)f2bf_rne(b) << 16);
}

// dvis[n] = (Dv[n,n]+eps)^-1/2 (0 pad); de_inv[e] = 1/(De[e,e]+eps) (0 pad)
__global__ void prep_diag_kernel(const float* __restrict__ Dv, const float* __restrict__ De,
                                 float* __restrict__ dvis, float* __restrict__ de_inv) {
    int i = blockIdx.x * 256 + threadIdx.x;
    if (i < NPAD) dvis[i] = (i < Nv) ? rsqrtf(Dv[(size_t)i * (Nv + 1)] + EPSF) : 0.0f;
    if (i < EW)   de_inv[i] = (i < Ne) ? 1.0f / (De[(size_t)i * (Ne + 1)] + EPSF) : 0.0f;
}

// sum(F*F) -> ws0[0]; block-level reduce -> 625 atomics total
__global__ void sum_ff_kernel(const float* __restrict__ F, float* __restrict__ out0) {
    __shared__ float red[4];
    const float4* F4 = (const float4*)F;
    int base = blockIdx.x * 512 + threadIdx.x;      // 625*512 = 320000 = N*d/4 exactly
    float4 a = F4[base];
    float4 b = F4[base + 256];
    float sum = a.x*a.x + a.y*a.y + a.z*a.z + a.w*a.w
              + b.x*b.x + b.y*b.y + b.z*b.z + b.w*b.w;
    #pragma unroll
    for (int off = 32; off; off >>= 1) sum += __shfl_down(sum, off);
    if ((threadIdx.x & 63) == 0) red[threadIdx.x >> 6] = sum;
    __syncthreads();
    if (threadIdx.x == 0) atomicAdd(out0, red[0] + red[1] + red[2] + red[3]);
}

// F[n][c]*dvis[n] -> Fst[c][n] bf16 via LDS tile transpose (coalesced both sides)
__global__ void transpose_f_kernel(const float* __restrict__ F, const float* __restrict__ dvis,
                                   unsigned short* __restrict__ Fst) {
    __shared__ float lds[32][33];
    const int t  = threadIdx.x;
    const int n0 = blockIdx.x * 32;
    const int c0 = blockIdx.y * 32;
    {
        const int r  = t >> 3;
        const int c4 = (t & 7) * 4;
        const int n  = n0 + r;
        float4 v = {0.f, 0.f, 0.f, 0.f};
        if (n < Nv) {
            v = *(const float4*)(F + (size_t)n * Dd + c0 + c4);
            float s = dvis[n];
            v.x *= s; v.y *= s; v.z *= s; v.w *= s;
        }
        lds[r][c4+0]=v.x; lds[r][c4+1]=v.y; lds[r][c4+2]=v.z; lds[r][c4+3]=v.w;
    }
    __syncthreads();
    {
        const int cr = t >> 3;          // c-local
        const int n4 = (t & 7) * 4;     // n-local base
        uint2 p = make_uint2(pack2(lds[n4+0][cr], lds[n4+1][cr]),
                             pack2(lds[n4+2][cr], lds[n4+3][cr]));
        *(uint2*)(Fst + (size_t)(c0 + cr) * NPAD + n0 + n4) = p;
    }
}

// H[n][e] -> Hbt packed B-fragment layout: Hbt[(et*NT16+s)*64 + lane][j0..7] bf16,
// value(lane,j) = H[s*16 + (lane>>5)*8 + j][et*32 + (lane&31)].
// GEMM B-load becomes one fully-contiguous 1KB dwordx4 per wave-step.
__global__ void transpose_h_kernel(const float* __restrict__ H, unsigned short* __restrict__ Hbt) {
    __shared__ float lds[32][33];
    const int t  = threadIdx.x;
    const int n0 = blockIdx.x * 32;
    const int e0 = blockIdx.y * 32;
    {
        const int r  = t >> 3;
        const int c4 = (t & 7) * 4;
        const int n  = n0 + r;
        const int e  = e0 + c4;
        float4 v = {0.f, 0.f, 0.f, 0.f};
        if (n < Nv && e + 4 <= Ne)      // Ne%4==0 -> float4 fully valid or fully pad
            v = *(const float4*)(H + (size_t)n * Ne + e);
        lds[r][c4+0]=v.x; lds[r][c4+1]=v.y; lds[r][c4+2]=v.z; lds[r][c4+3]=v.w;
    }
    __syncthreads();
    {
        const int sl   = t >> 7;                         // cell 0/1 (16-n chunks)
        const int lane = (t >> 1) & 63;
        const int jh   = t & 1;
        const int em   = lane & 31;
        const int nb   = sl * 16 + (lane >> 5) * 8 + jh * 4;
        uint2 p = make_uint2(pack2(lds[nb+0][em], lds[nb+1][em]),
                             pack2(lds[nb+2][em], lds[nb+3][em]));
        const size_t s = (size_t)blockIdx.y * NT16 + blockIdx.x * 2 + sl;
        *(uint2*)(Hbt + (s * 64 + lane) * 8 + jh * 4) = p;
    }
}

// Split-K GEMM: no LDS, no barriers, no in-loop converts.
// A = Fst[c][n] (bf16, L2-hot, b128/lane), B = Hbt packed (1KB contiguous per wave-step).
__global__ __launch_bounds__(256, 4)
void gemm_kernel(const unsigned short* __restrict__ Hbt, const unsigned short* __restrict__ Fst,
                 float* __restrict__ Mp) {
    const int t    = threadIdx.x;
    const int w    = t >> 6;
    const int l    = t & 63;
    const int em   = l & 31;
    const int half = l >> 5;
    const int gw   = blockIdx.x * 4 + w;   // 0..2511
    const int et   = gw % ETILES;
    const int spl  = gw / ETILES;
    const int sb   = spl * SPS;

    const unsigned short* Bp = Hbt + ((size_t)(et * NT16 + sb) * 64 + l) * 8;
    const unsigned short* Ap = Fst + (size_t)em * NPAD + sb * 16 + half * 8;

    f32x16 acc[4];
    #pragma unroll
    for (int ct = 0; ct < 4; ++ct) acc[ct] = (f32x16)(0.0f);

    bf16x8 A0[4], A1[4], B0, B1;
    B0 = *(const bf16x8*)Bp;
    #pragma unroll
    for (int ct = 0; ct < 4; ++ct) A0[ct] = *(const bf16x8*)(Ap + (size_t)ct * 32 * NPAD);

    for (int i = 0; i < SPS; i += 2) {     // SPS=40 even; i+1 always valid
        B1 = *(const bf16x8*)(Bp + (size_t)(i + 1) * 512);
        #pragma unroll
        for (int ct = 0; ct < 4; ++ct)
            A1[ct] = *(const bf16x8*)(Ap + (size_t)ct * 32 * NPAD + (i + 1) * 16);
        #pragma unroll
        for (int ct = 0; ct < 4; ++ct)
            acc[ct] = __builtin_amdgcn_mfma_f32_32x32x16_bf16(A0[ct], B0, acc[ct], 0, 0, 0);

        if (i + 2 < SPS) {
            B0 = *(const bf16x8*)(Bp + (size_t)(i + 2) * 512);
            #pragma unroll
            for (int ct = 0; ct < 4; ++ct)
                A0[ct] = *(const bf16x8*)(Ap + (size_t)ct * 32 * NPAD + (i + 2) * 16);
        }
        #pragma unroll
        for (int ct = 0; ct < 4; ++ct)
            acc[ct] = __builtin_amdgcn_mfma_f32_32x32x16_bf16(A1[ct], B1, acc[ct], 0, 0, 0);
    }

    // D layout (32x32, HW-verified): col = lane&31 (=e), row = (r&3)+8*(r>>2)+4*half (=c)
    const int e = et * 32 + em;
    float* dst = Mp + (size_t)spl * 128 * EW;
    #pragma unroll
    for (int ct = 0; ct < 4; ++ct)
        #pragma unroll
        for (int r = 0; r < 16; ++r) {
            const int cl = (r & 3) + 8 * (r >> 2) + 4 * half;
            dst[(size_t)(ct * 32 + cl) * EW + e] = acc[ct][r];
        }
}

// S = sum_e de_inv[e] * sum_c (sum_spl Mp[spl][c][e])^2 ; block reduce -> 628 atomics
__global__ void reduce_m_kernel(const float* __restrict__ Mp, const float* __restrict__ de_inv,
                                float* __restrict__ outS) {
    __shared__ float red[4];
    int gid = blockIdx.x * 256 + threadIdx.x;   // 628*256 = 160768 = 128*(EW/4)
    int c   = gid / (EW / 4);
    int ei  = (gid % (EW / 4)) * 4;
    float4 m = {0.f, 0.f, 0.f, 0.f};
    #pragma unroll
    for (int sp = 0; sp < KSPLIT; ++sp) {
        float4 p = *(const float4*)(Mp + ((size_t)sp * 128 + c) * EW + ei);
        m.x += p.x; m.y += p.y; m.z += p.z; m.w += p.w;
    }
    float4 w4 = *(const float4*)(de_inv + ei);
    float sum = w4.x*m.x*m.x + w4.y*m.y*m.y + w4.z*m.z*m.z + w4.w*m.w*m.w;
    #pragma unroll
    for (int off = 32; off; off >>= 1) sum += __shfl_down(sum, off);
    if ((threadIdx.x & 63) == 0) red[threadIdx.x >> 6] = sum;
    __syncthreads();
    if (threadIdx.x == 0) atomicAdd(outS, red[0] + red[1] + red[2] + red[3]);
}

__global__ void final_kernel(const float* __restrict__ ws0, float* __restrict__ out) {
    out[0] = (ws0[0] - ws0[1]) * (1.0f / (float)Nv);
}

extern "C" void kernel_launch(void* const* d_in, const int* in_sizes, int n_in,
                              void* d_out, int out_size, void* d_ws, size_t ws_size,
                              hipStream_t stream) {
    (void)in_sizes; (void)n_in; (void)out_size; (void)ws_size;
    const float* F  = (const float*)d_in[0];
    const float* H  = (const float*)d_in[1];
    const float* Dv = (const float*)d_in[2];
    const float* De = (const float*)d_in[3];
    float* out = (float*)d_out;

    // ws: ws0(16f) | dvis[NPAD] | de_inv[EW] | Mp[KSPLIT*128*EW] | Fst[128*NPAD] | Hbt[EW*NPAD]
    float* ws0             = (float*)d_ws;
    float* dvis            = ws0 + 16;
    float* de_inv          = dvis + NPAD;
    float* Mp              = de_inv + EW;                         // 16B-aligned
    unsigned short* Fst    = (unsigned short*)(Mp + (size_t)KSPLIT * 128 * EW);
    unsigned short* Hbt    = Fst + (size_t)Dd * NPAD;             // ~147 MB total

    hipMemsetAsync(ws0, 0, 64, stream);           // scalar accumulators only

    prep_diag_kernel <<<NPAD / 256, 256, 0, stream>>>(Dv, De, dvis, de_inv);
    sum_ff_kernel    <<<625, 256, 0, stream>>>(F, ws0);
    transpose_f_kernel<<<dim3(NPAD / 32, Dd / 32), 256, 0, stream>>>(F, dvis, Fst);
    transpose_h_kernel<<<dim3(NPAD / 32, ETILES), 256, 0, stream>>>(H, Hbt);
    gemm_kernel      <<<(ETILES * KSPLIT) / 4, 256, 0, stream>>>(Hbt, Fst, Mp);
    reduce_m_kernel  <<<(128 * EW / 4) / 256, 256, 0, stream>>>(Mp, de_inv, ws0 + 1);
    final_kernel     <<<1, 1, 0, stream>>>(ws0, out);
}